// Round 13
// baseline (214.547 us; speedup 1.0000x reference)
//
#include <hip/hip_runtime.h>
#include <hip/hip_bf16.h>
#include <stdint.h>

typedef unsigned short u16;
typedef __attribute__((ext_vector_type(8))) __bf16 bf16x8;
typedef __attribute__((ext_vector_type(4))) float f32x4;

#define C_DIM 768
#define HALF_C 384
#define N_SEQ 2048
#define BATCH 8
#define M_TOT (BATCH * N_SEQ) /* 16384 */
#define BK 32
#define NT (C_DIM / BK) /* 24 K-tiles */
// 256x256 tile, 8 waves (2 M x 4 N), per-wave 128x64 = acc[8][4] frags.
// LDS: ring of 4 K-tiles per operand, 16 KB each -> 128 KiB total.
// R12: paired vmcnt (vmcnt(4) after odd t, drain at t=21).
// R13: 3 barriers/K-step — mid-step barrier removed (race ledger in notes:
// RAW slot-t via BAR1; WAR stage-B vs prior b-reads via BAR1+lgkm timing;
// BAR4 kept — it carries the a2-read/stage-A WAR).

__device__ __forceinline__ u16 f2bf(float f) {
    union { float f; unsigned u; } c; c.f = f;
    unsigned r = (c.u + 0x7FFFu + ((c.u >> 16) & 1u)) >> 16;
    return (u16)r;
}

// One fused prep launch (unchanged).
#define PREP_XBLK 12288
#define PREP_WBLK 576
#define PREP_SBLK 3072
__global__ __launch_bounds__(256) void prep_kernel(
    const float* __restrict__ feat,
    const float* __restrict__ Wq, const float* __restrict__ Wk,
    const float* __restrict__ Wqc, const float* __restrict__ Wkc,
    u16* __restrict__ xbf,
    u16* __restrict__ w0, u16* __restrict__ w1,
    u16* __restrict__ w2, u16* __restrict__ w3,
    uint32_t* __restrict__ cs_tab) {
    const int b = blockIdx.x, tid = threadIdx.x;
    if (b < PREP_XBLK + 4 * PREP_WBLK) {
        const float* src; u16* dst; int base;
        if (b < PREP_XBLK)                    { src = feat; dst = xbf; base = 0; }
        else if (b < PREP_XBLK + PREP_WBLK)   { src = Wq;  dst = w0; base = PREP_XBLK; }
        else if (b < PREP_XBLK + 2*PREP_WBLK) { src = Wk;  dst = w1; base = PREP_XBLK + PREP_WBLK; }
        else if (b < PREP_XBLK + 3*PREP_WBLK) { src = Wqc; dst = w2; base = PREP_XBLK + 2*PREP_WBLK; }
        else                                  { src = Wkc; dst = w3; base = PREP_XBLK + 3*PREP_WBLK; }
        const int i = (b - base) * 256 + tid;
        float4 v = ((const float4*)src)[i];
        ushort4 o;
        o.x = f2bf(v.x); o.y = f2bf(v.y); o.z = f2bf(v.z); o.w = f2bf(v.w);
        ((ushort4*)dst)[i] = o;
    } else {
        const int idx = (b - PREP_XBLK - 4 * PREP_WBLK) * 256 + tid; // [0, HALF_C*N_SEQ)
        const int ip  = idx >> 11;           // freq index (row of transposed table)
        const int pos = idx & (N_SEQ - 1);   // position  (col, contiguous per thread)
        float inv = powf(10000.0f, (-2.0f / (float)C_DIM) * (float)ip);
        float ang = (float)pos * inv;
        uint32_t c = f2bf(cosf(ang)), s = f2bf(sinf(ang));
        cs_tab[idx] = (s << 16) | c;   // low = cos, high = sin
    }
}

template<int N> __device__ __forceinline__ void vmwait();
template<> __device__ __forceinline__ void vmwait<4>() { asm volatile("s_waitcnt vmcnt(4)" ::: "memory"); }
template<> __device__ __forceinline__ void vmwait<0>() { asm volatile("s_waitcnt vmcnt(0)" ::: "memory"); }

__device__ __forceinline__ void async_load16(const void* src, void* dst_lds) {
    const __attribute__((address_space(1))) void* g =
        (const __attribute__((address_space(1))) void*)(uintptr_t)src;
    __attribute__((address_space(3))) void* l =
        (__attribute__((address_space(3))) void*)(unsigned)(uintptr_t)dst_lds;
    __builtin_amdgcn_global_load_lds(g, l, 16, 0, 0);
}

// Stage one 256-row x 32-col bf16 operand K-tile (16 KB) into a ring slot.
// LDS written linearly (gload_lds: uniform base + lane*16); swizzle applied by
// permuting the per-lane GLOBAL source (m173 pattern).
// st_16x32-family swizzle (R11, == m201 byte formula translated): logical
// (row m, k-slot s) lives at physical slot s ^ (((m>>3)&1)<<1).
__device__ __forceinline__ void stage32(const u16* __restrict__ gbase, int ld,
                                        u16* ldsbase, int wave, int lane) {
    const int s  = (lane & 3) ^ (((lane >> 5) & 1) << 1);
    const int rr = lane >> 2;  // row within 16-row chunk
    #pragma unroll
    for (int j = 0; j < 2; ++j) {
        const int chunk = wave * 2 + j;  // 0..15, each 16 rows
        const u16* src = gbase + (size_t)(chunk * 16 + rr) * ld + s * 8;
        u16* dst = ldsbase + chunk * 512;  // wave-uniform, 1024 B per wave-issue
        async_load16(src, dst);
    }
}

// acc[8][4] += A[256,768] x B[256,768]^T for this block's 256x256 tile.
// Ring-4: compute tile t from slot t&3 while tile t+3 streams into slot
// (t+3)&3 (dead since t-1). Paired counted vmcnt; 3 barriers per K-step.
__device__ __forceinline__ void gemm256_mainloop(
    const u16* __restrict__ A, const u16* __restrict__ B, int ld,
    u16* LdsA, u16* LdsB, f32x4 (&acc)[8][4], int wave, int lane) {

    #pragma unroll
    for (int t = 0; t < 3; ++t) {
        stage32(A + t * BK, ld, LdsA + t * 8192, wave, lane);
        stage32(B + t * BK, ld, LdsB + t * 8192, wave, lane);
    }
    __builtin_amdgcn_sched_barrier(0);
    vmwait<4>();   // tiles 0,1 landed; tile 2 in flight
    __builtin_amdgcn_s_barrier();
    __builtin_amdgcn_sched_barrier(0);

    const int r = lane & 15, sl = lane >> 4;
    // reader-side swizzle: phys slot = sl ^ (((r>>3)&1)<<1)
    const int lane_off = r * 32 + ((sl ^ (((r >> 3) & 1) << 1)) * 8);
    const int wm = wave >> 2, wn = wave & 3;
    const int a_base = lane_off + wm * 512;   // + mf*1024 per fragment
    const int b_base = lane_off + wn * 512;   // + nf*2048 per fragment

    #pragma unroll
    for (int t = 0; t < NT; ++t) {
        const u16* At = LdsA + (t & 3) * 8192;
        const u16* Bt = LdsB + (t & 3) * 8192;
        bf16x8 a[4], b[4], a2[4];

        // ---- phase 0: stage next A; read a,b; BAR; mf 0-3 x nf 0-3 ----
        if (t + 3 < NT) stage32(A + (t + 3) * BK, ld, LdsA + ((t + 3) & 3) * 8192, wave, lane);
        #pragma unroll
        for (int mf = 0; mf < 4; ++mf) a[mf] = *(const bf16x8*)(At + a_base + mf * 1024);
        #pragma unroll
        for (int nf = 0; nf < 4; ++nf) b[nf] = *(const bf16x8*)(Bt + b_base + nf * 2048);
        __builtin_amdgcn_sched_barrier(0);
        __builtin_amdgcn_s_barrier();
        __builtin_amdgcn_sched_barrier(0);
        __builtin_amdgcn_s_setprio(1);
        #pragma unroll
        for (int mf = 0; mf < 4; ++mf)
            #pragma unroll
            for (int nf = 0; nf < 4; ++nf)
                acc[mf][nf] = __builtin_amdgcn_mfma_f32_16x16x32_bf16(a[mf], b[nf], acc[mf][nf], 0, 0, 0);
        __builtin_amdgcn_s_setprio(0);
        // (R13: mid-step barrier removed — phase-1 reads may overlap MFMA-0)

        // ---- phase 1: stage next B; read a2; BAR; mf 4-7 x nf 0-3 (b reused) ----
        if (t + 3 < NT) stage32(B + (t + 3) * BK, ld, LdsB + ((t + 3) & 3) * 8192, wave, lane);
        #pragma unroll
        for (int mf = 0; mf < 4; ++mf) a2[mf] = *(const bf16x8*)(At + a_base + (mf + 4) * 1024);
        __builtin_amdgcn_sched_barrier(0);
        __builtin_amdgcn_s_barrier();
        __builtin_amdgcn_sched_barrier(0);
        __builtin_amdgcn_s_setprio(1);
        #pragma unroll
        for (int mf = 0; mf < 4; ++mf)
            #pragma unroll
            for (int nf = 0; nf < 4; ++nf)
                acc[mf + 4][nf] = __builtin_amdgcn_mfma_f32_16x16x32_bf16(a2[mf], b[nf], acc[mf + 4][nf], 0, 0, 0);
        __builtin_amdgcn_s_setprio(0);
        __builtin_amdgcn_sched_barrier(0);
        // paired counted waits (R12): only after odd t.
        if ((t & 1) == 1) {
            if (t < NT - 3)       vmwait<4>();
            else if (t == NT - 3) vmwait<0>();
        }
        __builtin_amdgcn_s_barrier();   // WAR guard for stage into slot (t+4)&3
        __builtin_amdgcn_sched_barrier(0);
    }
}

// out[m,d] = RoPE(x @ W^T + bias) as bf16; z selects projection.
// XCD-pinned A panels (bx = xcd*8 + widx&7). Epilogue v2 (R9): RoPE in-register,
// bf16 dump to (dead) ring LDS with bank swizzle, coalesced dwordx4 stores.
__global__ __launch_bounds__(512, 2) void proj_kernel(
    const u16* __restrict__ xbf,
    const u16* __restrict__ W0, const u16* __restrict__ W1,
    const u16* __restrict__ W2, const u16* __restrict__ W3,
    const float* __restrict__ b0, const float* __restrict__ b1,
    const float* __restrict__ b2, const float* __restrict__ b3,
    u16* __restrict__ o0, u16* __restrict__ o1, u16* __restrict__ o2, u16* __restrict__ o3,
    const uint32_t* __restrict__ cs_tab) {
    __shared__ __align__(16) u16 Lds[65536];   // 128 KiB: ring A | ring B, reused by epilogue
    u16* LdsA = Lds;
    u16* LdsB = Lds + 32768;
    const int tid = threadIdx.x, lane = tid & 63, wave = tid >> 6;
    const int bid = blockIdx.x;
    const int xcd = bid & 7, widx = bid >> 3;   // widx in [0,96)
    const int bx  = xcd * 8 + (widx & 7);       // xbf panel, pinned to this XCD
    const int t2  = widx >> 3;                  // 0..11 = z*3 + by
    const int z   = t2 / 3;
    const int by  = t2 - z * 3;
    const int m0 = bx * 256, n0 = by * 256;

    const u16*   W    = z == 0 ? W0 : z == 1 ? W1 : z == 2 ? W2 : W3;
    const float* bias = z == 0 ? b0 : z == 1 ? b1 : z == 2 ? b2 : b3;
    u16*         outp = z == 0 ? o0 : z == 1 ? o1 : z == 2 ? o2 : o3;

    f32x4 acc[8][4];
    #pragma unroll
    for (int x = 0; x < 8; ++x)
        #pragma unroll
        for (int y = 0; y < 4; ++y) acc[x][y] = f32x4{0.f, 0.f, 0.f, 0.f};

    gemm256_mainloop(xbf + (size_t)m0 * C_DIM, W + (size_t)n0 * C_DIM, C_DIM,
                     LdsA, LdsB, acc, wave, lane);

    // ---- epilogue v2 ----
    const int wm = wave >> 2, wn = wave & 3;
    const int g = lane >> 4, r = lane & 15;
    // (mainloop ends with vmwait<0> + s_barrier: all LDS traffic retired)
    #pragma unroll
    for (int nf = 0; nf < 4; ++nf) {
        const int colL = wn * 64 + nf * 16 + r;   // local col 0..255
        const int col  = n0 + colL;
        const float bv = bias[col];
        const float sgn = (col & 1) ? 1.0f : -1.0f;  // even d: -x_odd*sin ; odd d: +x_even*sin
        const uint32_t* csrow = cs_tab + (size_t)(col >> 1) * N_SEQ;
        #pragma unroll
        for (int mf = 0; mf < 8; ++mf) {
            const int rowb = m0 + mf * 32 + wm * 16 + g * 4;   // rows rowb..rowb+3
            const uint4 cs4 = *(const uint4*)(csrow + (rowb & (N_SEQ - 1)));
            #pragma unroll
            for (int i = 0; i < 4; ++i) {
                float v = acc[mf][nf][i] + bv;
                float p = __shfl_xor(v, 1);  // RoPE partner (col parity == lane parity)
                const uint32_t cs = ((const uint32_t*)&cs4)[i];
                const float c = __uint_as_float(cs << 16);
                const float s = __uint_as_float(cs & 0xFFFF0000u);
                const int rowL = mf * 32 + wm * 16 + g * 4 + i;
                const int ba = (rowL << 9) + colL * 2;          // [256][512B] tile
                *(u16*)((char*)Lds + (ba ^ (((rowL >> 2) & 3) << 5))) = f2bf(v * c + sgn * p * s);
            }
        }
    }
    __syncthreads();
    // readback (wave-uniform un-swizzle) + coalesced 16B stores: 1 KiB/wave-instr
    const size_t gbase = (size_t)m0 * C_DIM + n0;
    #pragma unroll
    for (int k = 0; k < 16; ++k) {
        const int f = (k * 512 + tid) * 16;
        const int row = f >> 9;
        const int cb  = f & 511;
        const uint4 vv = *(const uint4*)((const char*)Lds + (f ^ ((((unsigned)f >> 11) & 3) << 5)));
        *(uint4*)(outp + gbase + (size_t)row * C_DIM + (cb >> 1)) = vv;
    }
}

// out[z,n,m] = (Q[z,n,:].K[z,m,:])/sqrt(C) - (m<n)*1e10/sqrt(C);  z = h*8+b.
// Strictly-lower 256x256 blocks: reference fp32 computes (qk - 1e10) == -1e10
// exactly (qk << ulp(1e10)) -> constant write, skip the GEMM (28/64 per z).
__global__ __launch_bounds__(512, 2) void logits_kernel(
    const u16* __restrict__ Q0, const u16* __restrict__ K0,
    const u16* __restrict__ Q1, const u16* __restrict__ K1,
    float* __restrict__ out) {
    __shared__ __align__(16) u16 LdsA[4 * 8192];
    __shared__ __align__(16) u16 LdsB[4 * 8192];
    const int tid = threadIdx.x, lane = tid & 63, wave = tid >> 6;
    const int bid = blockIdx.x;
    const int swz = (bid & 7) * 128 + (bid >> 3);
    const int z   = swz >> 6;          // 0..15 = h*8+b
    const int rem = swz & 63;
    const int by  = rem >> 3;          // row (Q) block
    const int bx  = rem & 7;           // col (K) block
    const int nrow0 = by * 256, mcol0 = bx * 256;

    const float RS = 0.036084391824351613f;  // 1/sqrt(768)
    const float MV = 1.0e10f * RS;
    float* outz = out + (size_t)z * N_SEQ * N_SEQ;

    if (bx < by) {  // fully-masked block: constant write, coalesced 1 KiB/wave stores
        const float4 cv = {-MV, -MV, -MV, -MV};
        #pragma unroll
        for (int i = 0; i < 32; ++i) {
            const int row = nrow0 + wave * 32 + i;
            *(float4*)(outz + (size_t)row * N_SEQ + mcol0 + lane * 4) = cv;
        }
        return;
    }

    const int h = z >> 3, b = z & 7;
    const u16* Qb = (h ? Q1 : Q0) + (size_t)b * N_SEQ * C_DIM;
    const u16* Kb = (h ? K1 : K0) + (size_t)b * N_SEQ * C_DIM;

    f32x4 acc[8][4];
    #pragma unroll
    for (int x = 0; x < 8; ++x)
        #pragma unroll
        for (int y = 0; y < 4; ++y) acc[x][y] = f32x4{0.f, 0.f, 0.f, 0.f};

    gemm256_mainloop(Qb + (size_t)nrow0 * C_DIM, Kb + (size_t)mcol0 * C_DIM, C_DIM,
                     LdsA, LdsB, acc, wave, lane);

    const int wm = wave >> 2, wn = wave & 3;
    const int g = lane >> 4, r = lane & 15;
    #pragma unroll
    for (int mf = 0; mf < 8; ++mf) {
        #pragma unroll
        for (int i = 0; i < 4; ++i) {
            const int row = nrow0 + mf * 32 + wm * 16 + g * 4 + i;
            float* orow = outz + (size_t)row * N_SEQ;
            #pragma unroll
            for (int nf = 0; nf < 4; ++nf) {
                const int col = mcol0 + wn * 64 + nf * 16 + r;
                orow[col] = acc[mf][nf][i] * RS - (col < row ? MV : 0.0f);
            }
        }
    }
}

extern "C" void kernel_launch(void* const* d_in, const int* in_sizes, int n_in,
                              void* d_out, int out_size, void* d_ws, size_t ws_size,
                              hipStream_t stream) {
    (void)in_sizes; (void)n_in; (void)out_size; (void)ws_size;
    const float* feat = (const float*)d_in[0];
    const float* Wq   = (const float*)d_in[1];
    const float* bq   = (const float*)d_in[2];
    const float* Wk   = (const float*)d_in[3];
    const float* bk   = (const float*)d_in[4];
    const float* Wqc  = (const float*)d_in[5];
    const float* bqc  = (const float*)d_in[6];
    const float* Wkc  = (const float*)d_in[7];
    const float* bkc  = (const float*)d_in[8];
    float* out = (float*)d_out;

    // workspace layout (u16 elements): x_bf | W_bf[4] | Q0 K0 Q1 K1 | cs_tab (u32, [HALF_C][N_SEQ])
    u16* ws = (u16*)d_ws;
    const size_t XE = (size_t)M_TOT * C_DIM;   // 12,582,912
    const size_t WE = (size_t)C_DIM * C_DIM;   // 589,824
    u16* xbf = ws;
    u16* Wb0 = ws + XE;
    u16* Wb1 = Wb0 + WE;
    u16* Wb2 = Wb1 + WE;
    u16* Wb3 = Wb2 + WE;
    u16* qkbase = Wb3 + WE;
    u16* Qa = qkbase;            // proj0: Wq
    u16* Ka = qkbase + XE;       // proj1: Wk
    u16* Qc = qkbase + 2 * XE;   // proj2: Wq_cls
    u16* Kc = qkbase + 3 * XE;   // proj3: Wk_cls
    uint32_t* cs_tab = (uint32_t*)(qkbase + 4 * XE);

    prep_kernel<<<dim3(PREP_XBLK + 4 * PREP_WBLK + PREP_SBLK), dim3(256), 0, stream>>>(
        feat, Wq, Wk, Wqc, Wkc, xbf, Wb0, Wb1, Wb2, Wb3, cs_tab);

    proj_kernel<<<dim3(768), dim3(512), 0, stream>>>(
        xbf, Wb0, Wb1, Wb2, Wb3, bq, bk, bqc, bkc, Qa, Ka, Qc, Kc, cs_tab);

    logits_kernel<<<dim3(1024), dim3(512), 0, stream>>>(
        Qa, Ka, Qc, Kc, out);
}

// Round 14
// 212.030 us; speedup vs baseline: 1.0119x; 1.0119x over previous
//
#include <hip/hip_runtime.h>
#include <hip/hip_bf16.h>
#include <stdint.h>

typedef unsigned short u16;
typedef __attribute__((ext_vector_type(8))) __bf16 bf16x8;
typedef __attribute__((ext_vector_type(4))) float f32x4;

#define C_DIM 768
#define HALF_C 384
#define N_SEQ 2048
#define BATCH 8
#define M_TOT (BATCH * N_SEQ) /* 16384 */
#define BK 32
#define NT (C_DIM / BK) /* 24 K-tiles */
// 256x256 tile, 8 waves (2 M x 4 N), per-wave 128x64 = acc[8][4] frags.
// LDS: ring of 4 K-tiles per operand, 16 KB each -> 128 KiB total.
// R14: template-derived wait ladder — vmcnt(8) at EVERY tile end (4 stages /
// 8 loads in flight; gates tile t+1's B-half exactly), tail 4@21, 0@22;
// ds-reads issued BEFORE stage in each phase (m201 phase order).
// 4 barriers/K-step (R13 proved the mid-step barrier is load-bearing).

__device__ __forceinline__ u16 f2bf(float f) {
    union { float f; unsigned u; } c; c.f = f;
    unsigned r = (c.u + 0x7FFFu + ((c.u >> 16) & 1u)) >> 16;
    return (u16)r;
}

// Fused prep, grid-stride (R14): 2048 blocks x 256 thr.
//   conv space: feature (3,145,728 float4) then 4 weights (147,456 each)
//   cs space:   packed (cos,sin) bf16x2 table, TRANSPOSED [HALF_C][N_SEQ]
#define NXF4   3145728
#define NWF4   147456
#define NCONV4 (NXF4 + 4 * NWF4)
#define NCS    (N_SEQ * HALF_C)
__global__ __launch_bounds__(256) void prep_kernel(
    const float* __restrict__ feat,
    const float* __restrict__ Wq, const float* __restrict__ Wk,
    const float* __restrict__ Wqc, const float* __restrict__ Wkc,
    u16* __restrict__ xbf,
    u16* __restrict__ w0, u16* __restrict__ w1,
    u16* __restrict__ w2, u16* __restrict__ w3,
    uint32_t* __restrict__ cs_tab) {
    const int gid = blockIdx.x * 256 + threadIdx.x;
    const int stride = gridDim.x * 256;
    for (int i = gid; i < NCONV4; i += stride) {
        const float* src; u16* dst; int j;
        if (i < NXF4) { src = feat; dst = xbf; j = i; }
        else {
            const int k = i - NXF4;
            const int w = k / NWF4;
            j = k - w * NWF4;
            src = w == 0 ? Wq : w == 1 ? Wk : w == 2 ? Wqc : Wkc;
            dst = w == 0 ? w0 : w == 1 ? w1 : w == 2 ? w2 : w3;
        }
        float4 v = ((const float4*)src)[j];
        ushort4 o;
        o.x = f2bf(v.x); o.y = f2bf(v.y); o.z = f2bf(v.z); o.w = f2bf(v.w);
        ((ushort4*)dst)[j] = o;
    }
    for (int idx = gid; idx < NCS; idx += stride) {
        const int ip  = idx >> 11;           // freq index (row of transposed table)
        const int pos = idx & (N_SEQ - 1);   // position  (col, contiguous)
        float inv = powf(10000.0f, (-2.0f / (float)C_DIM) * (float)ip);
        float ang = (float)pos * inv;
        uint32_t c = f2bf(cosf(ang)), s = f2bf(sinf(ang));
        cs_tab[idx] = (s << 16) | c;   // low = cos, high = sin
    }
}

template<int N> __device__ __forceinline__ void vmwait();
template<> __device__ __forceinline__ void vmwait<8>() { asm volatile("s_waitcnt vmcnt(8)" ::: "memory"); }
template<> __device__ __forceinline__ void vmwait<4>() { asm volatile("s_waitcnt vmcnt(4)" ::: "memory"); }
template<> __device__ __forceinline__ void vmwait<0>() { asm volatile("s_waitcnt vmcnt(0)" ::: "memory"); }

__device__ __forceinline__ void async_load16(const void* src, void* dst_lds) {
    const __attribute__((address_space(1))) void* g =
        (const __attribute__((address_space(1))) void*)(uintptr_t)src;
    __attribute__((address_space(3))) void* l =
        (__attribute__((address_space(3))) void*)(unsigned)(uintptr_t)dst_lds;
    __builtin_amdgcn_global_load_lds(g, l, 16, 0, 0);
}

// Stage one 256-row x 32-col bf16 operand K-tile (16 KB) into a ring slot.
// LDS written linearly (gload_lds: uniform base + lane*16); swizzle applied by
// permuting the per-lane GLOBAL source (m173 pattern).
// st_16x32-family swizzle (R11): logical (row m, k-slot s) at phys
// slot s ^ (((m>>3)&1)<<1).
__device__ __forceinline__ void stage32(const u16* __restrict__ gbase, int ld,
                                        u16* ldsbase, int wave, int lane) {
    const int s  = (lane & 3) ^ (((lane >> 5) & 1) << 1);
    const int rr = lane >> 2;  // row within 16-row chunk
    #pragma unroll
    for (int j = 0; j < 2; ++j) {
        const int chunk = wave * 2 + j;  // 0..15, each 16 rows
        const u16* src = gbase + (size_t)(chunk * 16 + rr) * ld + s * 8;
        u16* dst = ldsbase + chunk * 512;  // wave-uniform, 1024 B per wave-issue
        async_load16(src, dst);
    }
}

// acc[8][4] += A[256,768] x B[256,768]^T for this block's 256x256 tile.
// Ring-4: compute tile t from slot t&3 while tile t+3 streams into slot
// (t+3)&3 (dead since t-1). vmcnt(8) at every tile end (R14 ladder).
__device__ __forceinline__ void gemm256_mainloop(
    const u16* __restrict__ A, const u16* __restrict__ B, int ld,
    u16* LdsA, u16* LdsB, f32x4 (&acc)[8][4], int wave, int lane) {

    #pragma unroll
    for (int t = 0; t < 3; ++t) {
        stage32(A + t * BK, ld, LdsA + t * 8192, wave, lane);
        stage32(B + t * BK, ld, LdsB + t * 8192, wave, lane);
    }
    __builtin_amdgcn_sched_barrier(0);
    vmwait<8>();   // A(0),B(0) landed (items 1,2 of 6)
    __builtin_amdgcn_s_barrier();
    __builtin_amdgcn_sched_barrier(0);

    const int r = lane & 15, sl = lane >> 4;
    // reader-side swizzle: phys slot = sl ^ (((r>>3)&1)<<1)
    const int lane_off = r * 32 + ((sl ^ (((r >> 3) & 1) << 1)) * 8);
    const int wm = wave >> 2, wn = wave & 3;
    const int a_base = lane_off + wm * 512;   // + mf*1024 per fragment
    const int b_base = lane_off + wn * 512;   // + nf*2048 per fragment

    #pragma unroll
    for (int t = 0; t < NT; ++t) {
        const u16* At = LdsA + (t & 3) * 8192;
        const u16* Bt = LdsB + (t & 3) * 8192;
        bf16x8 a[4], b[4], a2[4];

        // ---- phase 0: read a,b (first); stage next A; BAR; mf 0-3 ----
        #pragma unroll
        for (int mf = 0; mf < 4; ++mf) a[mf] = *(const bf16x8*)(At + a_base + mf * 1024);
        #pragma unroll
        for (int nf = 0; nf < 4; ++nf) b[nf] = *(const bf16x8*)(Bt + b_base + nf * 2048);
        if (t + 3 < NT) stage32(A + (t + 3) * BK, ld, LdsA + ((t + 3) & 3) * 8192, wave, lane);
        __builtin_amdgcn_sched_barrier(0);
        __builtin_amdgcn_s_barrier();
        __builtin_amdgcn_sched_barrier(0);
        __builtin_amdgcn_s_setprio(1);
        #pragma unroll
        for (int mf = 0; mf < 4; ++mf)
            #pragma unroll
            for (int nf = 0; nf < 4; ++nf)
                acc[mf][nf] = __builtin_amdgcn_mfma_f32_16x16x32_bf16(a[mf], b[nf], acc[mf][nf], 0, 0, 0);
        __builtin_amdgcn_s_setprio(0);
        __builtin_amdgcn_sched_barrier(0);
        __builtin_amdgcn_s_barrier();
        __builtin_amdgcn_sched_barrier(0);

        // ---- phase 1: read a2 (first); stage next B; BAR; mf 4-7 (b reused) ----
        #pragma unroll
        for (int mf = 0; mf < 4; ++mf) a2[mf] = *(const bf16x8*)(At + a_base + (mf + 4) * 1024);
        if (t + 3 < NT) stage32(B + (t + 3) * BK, ld, LdsB + ((t + 3) & 3) * 8192, wave, lane);
        __builtin_amdgcn_sched_barrier(0);
        __builtin_amdgcn_s_barrier();
        __builtin_amdgcn_sched_barrier(0);
        __builtin_amdgcn_s_setprio(1);
        #pragma unroll
        for (int mf = 0; mf < 4; ++mf)
            #pragma unroll
            for (int nf = 0; nf < 4; ++nf)
                acc[mf + 4][nf] = __builtin_amdgcn_mfma_f32_16x16x32_bf16(a2[mf], b[nf], acc[mf + 4][nf], 0, 0, 0);
        __builtin_amdgcn_s_setprio(0);
        __builtin_amdgcn_sched_barrier(0);
        // R14 ladder: gate tile t+1's halves exactly, every tile end.
        // B(t+1) staged at (t-2).ph1; stages issued after it = 4 = 8 loads.
        if (t <= NT - 4)      vmwait<8>();
        else if (t == NT - 3) vmwait<4>();   // t=21: only A23,B23 outstanding after gate
        else if (t == NT - 2) vmwait<0>();   // t=22: drain (covers epilogue LDS reuse)
        __builtin_amdgcn_s_barrier();
        __builtin_amdgcn_sched_barrier(0);
    }
}

// out[m,d] = RoPE(x @ W^T + bias) as bf16; z selects projection.
// XCD-pinned A panels (bx = xcd*8 + widx&7). Epilogue v2 (R9): RoPE in-register,
// bf16 dump to (dead) ring LDS with bank swizzle, coalesced dwordx4 stores.
__global__ __launch_bounds__(512, 2) void proj_kernel(
    const u16* __restrict__ xbf,
    const u16* __restrict__ W0, const u16* __restrict__ W1,
    const u16* __restrict__ W2, const u16* __restrict__ W3,
    const float* __restrict__ b0, const float* __restrict__ b1,
    const float* __restrict__ b2, const float* __restrict__ b3,
    u16* __restrict__ o0, u16* __restrict__ o1, u16* __restrict__ o2, u16* __restrict__ o3,
    const uint32_t* __restrict__ cs_tab) {
    __shared__ __align__(16) u16 Lds[65536];   // 128 KiB: ring A | ring B, reused by epilogue
    u16* LdsA = Lds;
    u16* LdsB = Lds + 32768;
    const int tid = threadIdx.x, lane = tid & 63, wave = tid >> 6;
    const int bid = blockIdx.x;
    const int xcd = bid & 7, widx = bid >> 3;   // widx in [0,96)
    const int bx  = xcd * 8 + (widx & 7);       // xbf panel, pinned to this XCD
    const int t2  = widx >> 3;                  // 0..11 = z*3 + by
    const int z   = t2 / 3;
    const int by  = t2 - z * 3;
    const int m0 = bx * 256, n0 = by * 256;

    const u16*   W    = z == 0 ? W0 : z == 1 ? W1 : z == 2 ? W2 : W3;
    const float* bias = z == 0 ? b0 : z == 1 ? b1 : z == 2 ? b2 : b3;
    u16*         outp = z == 0 ? o0 : z == 1 ? o1 : z == 2 ? o2 : o3;

    f32x4 acc[8][4];
    #pragma unroll
    for (int x = 0; x < 8; ++x)
        #pragma unroll
        for (int y = 0; y < 4; ++y) acc[x][y] = f32x4{0.f, 0.f, 0.f, 0.f};

    gemm256_mainloop(xbf + (size_t)m0 * C_DIM, W + (size_t)n0 * C_DIM, C_DIM,
                     LdsA, LdsB, acc, wave, lane);

    // ---- epilogue v2 ----
    const int wm = wave >> 2, wn = wave & 3;
    const int g = lane >> 4, r = lane & 15;
    // (mainloop ends with vmwait<0> @t=22 + final barrier: LDS traffic retired)
    #pragma unroll
    for (int nf = 0; nf < 4; ++nf) {
        const int colL = wn * 64 + nf * 16 + r;   // local col 0..255
        const int col  = n0 + colL;
        const float bv = bias[col];
        const float sgn = (col & 1) ? 1.0f : -1.0f;  // even d: -x_odd*sin ; odd d: +x_even*sin
        const uint32_t* csrow = cs_tab + (size_t)(col >> 1) * N_SEQ;
        #pragma unroll
        for (int mf = 0; mf < 8; ++mf) {
            const int rowb = m0 + mf * 32 + wm * 16 + g * 4;   // rows rowb..rowb+3
            const uint4 cs4 = *(const uint4*)(csrow + (rowb & (N_SEQ - 1)));
            #pragma unroll
            for (int i = 0; i < 4; ++i) {
                float v = acc[mf][nf][i] + bv;
                float p = __shfl_xor(v, 1);  // RoPE partner (col parity == lane parity)
                const uint32_t cs = ((const uint32_t*)&cs4)[i];
                const float c = __uint_as_float(cs << 16);
                const float s = __uint_as_float(cs & 0xFFFF0000u);
                const int rowL = mf * 32 + wm * 16 + g * 4 + i;
                const int ba = (rowL << 9) + colL * 2;          // [256][512B] tile
                *(u16*)((char*)Lds + (ba ^ (((rowL >> 2) & 3) << 5))) = f2bf(v * c + sgn * p * s);
            }
        }
    }
    __syncthreads();
    // readback (wave-uniform un-swizzle) + coalesced 16B stores: 1 KiB/wave-instr
    const size_t gbase = (size_t)m0 * C_DIM + n0;
    #pragma unroll
    for (int k = 0; k < 16; ++k) {
        const int f = (k * 512 + tid) * 16;
        const int row = f >> 9;
        const int cb  = f & 511;
        const uint4 vv = *(const uint4*)((const char*)Lds + (f ^ ((((unsigned)f >> 11) & 3) << 5)));
        *(uint4*)(outp + gbase + (size_t)row * C_DIM + (cb >> 1)) = vv;
    }
}

// out[z,n,m] = (Q[z,n,:].K[z,m,:])/sqrt(C) - (m<n)*1e10/sqrt(C);  z = h*8+b.
// Strictly-lower 256x256 blocks: reference fp32 computes (qk - 1e10) == -1e10
// exactly (qk << ulp(1e10)) -> constant write, skip the GEMM (28/64 per z).
__global__ __launch_bounds__(512, 2) void logits_kernel(
    const u16* __restrict__ Q0, const u16* __restrict__ K0,
    const u16* __restrict__ Q1, const u16* __restrict__ K1,
    float* __restrict__ out) {
    __shared__ __align__(16) u16 LdsA[4 * 8192];
    __shared__ __align__(16) u16 LdsB[4 * 8192];
    const int tid = threadIdx.x, lane = tid & 63, wave = tid >> 6;
    const int bid = blockIdx.x;
    const int swz = (bid & 7) * 128 + (bid >> 3);
    const int z   = swz >> 6;          // 0..15 = h*8+b
    const int rem = swz & 63;
    const int by  = rem >> 3;          // row (Q) block
    const int bx  = rem & 7;           // col (K) block
    const int nrow0 = by * 256, mcol0 = bx * 256;

    const float RS = 0.036084391824351613f;  // 1/sqrt(768)
    const float MV = 1.0e10f * RS;
    float* outz = out + (size_t)z * N_SEQ * N_SEQ;

    if (bx < by) {  // fully-masked block: constant write, coalesced 1 KiB/wave stores
        const float4 cv = {-MV, -MV, -MV, -MV};
        #pragma unroll
        for (int i = 0; i < 32; ++i) {
            const int row = nrow0 + wave * 32 + i;
            *(float4*)(outz + (size_t)row * N_SEQ + mcol0 + lane * 4) = cv;
        }
        return;
    }

    const int h = z >> 3, b = z & 7;
    const u16* Qb = (h ? Q1 : Q0) + (size_t)b * N_SEQ * C_DIM;
    const u16* Kb = (h ? K1 : K0) + (size_t)b * N_SEQ * C_DIM;

    f32x4 acc[8][4];
    #pragma unroll
    for (int x = 0; x < 8; ++x)
        #pragma unroll
        for (int y = 0; y < 4; ++y) acc[x][y] = f32x4{0.f, 0.f, 0.f, 0.f};

    gemm256_mainloop(Qb + (size_t)nrow0 * C_DIM, Kb + (size_t)mcol0 * C_DIM, C_DIM,
                     LdsA, LdsB, acc, wave, lane);

    const int wm = wave >> 2, wn = wave & 3;
    const int g = lane >> 4, r = lane & 15;
    #pragma unroll
    for (int mf = 0; mf < 8; ++mf) {
        #pragma unroll
        for (int i = 0; i < 4; ++i) {
            const int row = nrow0 + mf * 32 + wm * 16 + g * 4 + i;
            float* orow = outz + (size_t)row * N_SEQ;
            #pragma unroll
            for (int nf = 0; nf < 4; ++nf) {
                const int col = mcol0 + wn * 64 + nf * 16 + r;
                orow[col] = acc[mf][nf][i] * RS - (col < row ? MV : 0.0f);
            }
        }
    }
}

extern "C" void kernel_launch(void* const* d_in, const int* in_sizes, int n_in,
                              void* d_out, int out_size, void* d_ws, size_t ws_size,
                              hipStream_t stream) {
    (void)in_sizes; (void)n_in; (void)out_size; (void)ws_size;
    const float* feat = (const float*)d_in[0];
    const float* Wq   = (const float*)d_in[1];
    const float* bq   = (const float*)d_in[2];
    const float* Wk   = (const float*)d_in[3];
    const float* bk   = (const float*)d_in[4];
    const float* Wqc  = (const float*)d_in[5];
    const float* bqc  = (const float*)d_in[6];
    const float* Wkc  = (const float*)d_in[7];
    const float* bkc  = (const float*)d_in[8];
    float* out = (float*)d_out;

    // workspace layout (u16 elements): x_bf | W_bf[4] | Q0 K0 Q1 K1 | cs_tab (u32, [HALF_C][N_SEQ])
    u16* ws = (u16*)d_ws;
    const size_t XE = (size_t)M_TOT * C_DIM;   // 12,582,912
    const size_t WE = (size_t)C_DIM * C_DIM;   // 589,824
    u16* xbf = ws;
    u16* Wb0 = ws + XE;
    u16* Wb1 = Wb0 + WE;
    u16* Wb2 = Wb1 + WE;
    u16* Wb3 = Wb2 + WE;
    u16* qkbase = Wb3 + WE;
    u16* Qa = qkbase;            // proj0: Wq
    u16* Ka = qkbase + XE;       // proj1: Wk
    u16* Qc = qkbase + 2 * XE;   // proj2: Wq_cls
    u16* Kc = qkbase + 3 * XE;   // proj3: Wk_cls
    uint32_t* cs_tab = (uint32_t*)(qkbase + 4 * XE);

    prep_kernel<<<dim3(2048), dim3(256), 0, stream>>>(
        feat, Wq, Wk, Wqc, Wkc, xbf, Wb0, Wb1, Wb2, Wb3, cs_tab);

    proj_kernel<<<dim3(768), dim3(512), 0, stream>>>(
        xbf, Wb0, Wb1, Wb2, Wb3, bq, bk, bqc, bkc, Qa, Ka, Qc, Kc, cs_tab);

    logits_kernel<<<dim3(1024), dim3(512), 0, stream>>>(
        Qa, Ka, Qc, Kc, out);
}

// Round 16
// 202.092 us; speedup vs baseline: 1.0616x; 1.0492x over previous
//
#include <hip/hip_runtime.h>
#include <hip/hip_bf16.h>
#include <stdint.h>

typedef unsigned short u16;
typedef __attribute__((ext_vector_type(8))) __bf16 bf16x8;
typedef __attribute__((ext_vector_type(4))) float f32x4;

#define C_DIM 768
#define HALF_C 384
#define N_SEQ 2048
#define BATCH 8
#define M_TOT (BATCH * N_SEQ) /* 16384 */
#define BK 32
#define NT (C_DIM / BK) /* 24 K-tiles */
// 256x256 tile, 8 waves (2 M x 4 N), per-wave 128x64 = acc[8][4] frags.
// LDS: ring of 4 K-tiles per operand, 16 KB each -> 128 KiB total.
// R12 schedule (best): 2 phases/K-step, 4 barriers, stage-before-reads,
// paired vmcnt (vmcnt(4) after odd t, drain at t=21).
// R15/16: non-temporal stores on logits output (write-once stream; stop
// evicting Q/K panels from L2/L3). NT store needs clang-native vector type
// (f32x4), not HIP float4 — R15 compile fix.

__device__ __forceinline__ u16 f2bf(float f) {
    union { float f; unsigned u; } c; c.f = f;
    unsigned r = (c.u + 0x7FFFu + ((c.u >> 16) & 1u)) >> 16;
    return (u16)r;
}

// Fused prep, grid-stride (R14): 2048 blocks x 256 thr.
#define NXF4   3145728
#define NWF4   147456
#define NCONV4 (NXF4 + 4 * NWF4)
#define NCS    (N_SEQ * HALF_C)
__global__ __launch_bounds__(256) void prep_kernel(
    const float* __restrict__ feat,
    const float* __restrict__ Wq, const float* __restrict__ Wk,
    const float* __restrict__ Wqc, const float* __restrict__ Wkc,
    u16* __restrict__ xbf,
    u16* __restrict__ w0, u16* __restrict__ w1,
    u16* __restrict__ w2, u16* __restrict__ w3,
    uint32_t* __restrict__ cs_tab) {
    const int gid = blockIdx.x * 256 + threadIdx.x;
    const int stride = gridDim.x * 256;
    for (int i = gid; i < NCONV4; i += stride) {
        const float* src; u16* dst; int j;
        if (i < NXF4) { src = feat; dst = xbf; j = i; }
        else {
            const int k = i - NXF4;
            const int w = k / NWF4;
            j = k - w * NWF4;
            src = w == 0 ? Wq : w == 1 ? Wk : w == 2 ? Wqc : Wkc;
            dst = w == 0 ? w0 : w == 1 ? w1 : w == 2 ? w2 : w3;
        }
        float4 v = ((const float4*)src)[j];
        ushort4 o;
        o.x = f2bf(v.x); o.y = f2bf(v.y); o.z = f2bf(v.z); o.w = f2bf(v.w);
        ((ushort4*)dst)[j] = o;
    }
    for (int idx = gid; idx < NCS; idx += stride) {
        const int ip  = idx >> 11;           // freq index (row of transposed table)
        const int pos = idx & (N_SEQ - 1);   // position  (col, contiguous)
        float inv = powf(10000.0f, (-2.0f / (float)C_DIM) * (float)ip);
        float ang = (float)pos * inv;
        uint32_t c = f2bf(cosf(ang)), s = f2bf(sinf(ang));
        cs_tab[idx] = (s << 16) | c;   // low = cos, high = sin
    }
}

template<int N> __device__ __forceinline__ void vmwait();
template<> __device__ __forceinline__ void vmwait<4>() { asm volatile("s_waitcnt vmcnt(4)" ::: "memory"); }
template<> __device__ __forceinline__ void vmwait<0>() { asm volatile("s_waitcnt vmcnt(0)" ::: "memory"); }

__device__ __forceinline__ void async_load16(const void* src, void* dst_lds) {
    const __attribute__((address_space(1))) void* g =
        (const __attribute__((address_space(1))) void*)(uintptr_t)src;
    __attribute__((address_space(3))) void* l =
        (__attribute__((address_space(3))) void*)(unsigned)(uintptr_t)dst_lds;
    __builtin_amdgcn_global_load_lds(g, l, 16, 0, 0);
}

// Stage one 256-row x 32-col bf16 operand K-tile (16 KB) into a ring slot.
// LDS written linearly (gload_lds: uniform base + lane*16); swizzle applied by
// permuting the per-lane GLOBAL source (m173 pattern).
// st_16x32-family swizzle (R11, == m201 byte formula translated): logical
// (row m, k-slot s) lives at physical slot s ^ (((m>>3)&1)<<1).
__device__ __forceinline__ void stage32(const u16* __restrict__ gbase, int ld,
                                        u16* ldsbase, int wave, int lane) {
    const int s  = (lane & 3) ^ (((lane >> 5) & 1) << 1);
    const int rr = lane >> 2;  // row within 16-row chunk
    #pragma unroll
    for (int j = 0; j < 2; ++j) {
        const int chunk = wave * 2 + j;  // 0..15, each 16 rows
        const u16* src = gbase + (size_t)(chunk * 16 + rr) * ld + s * 8;
        u16* dst = ldsbase + chunk * 512;  // wave-uniform, 1024 B per wave-issue
        async_load16(src, dst);
    }
}

// acc[8][4] += A[256,768] x B[256,768]^T for this block's 256x256 tile.
// Ring-4: compute tile t from slot t&3 while tile t+3 streams into slot
// (t+3)&3 (dead since t-1). Paired counted vmcnt (R12), 4 barriers/K-step.
__device__ __forceinline__ void gemm256_mainloop(
    const u16* __restrict__ A, const u16* __restrict__ B, int ld,
    u16* LdsA, u16* LdsB, f32x4 (&acc)[8][4], int wave, int lane) {

    #pragma unroll
    for (int t = 0; t < 3; ++t) {
        stage32(A + t * BK, ld, LdsA + t * 8192, wave, lane);
        stage32(B + t * BK, ld, LdsB + t * 8192, wave, lane);
    }
    __builtin_amdgcn_sched_barrier(0);
    vmwait<4>();   // tiles 0,1 landed; tile 2 in flight
    __builtin_amdgcn_s_barrier();
    __builtin_amdgcn_sched_barrier(0);

    const int r = lane & 15, sl = lane >> 4;
    // reader-side swizzle: phys slot = sl ^ (((r>>3)&1)<<1)
    const int lane_off = r * 32 + ((sl ^ (((r >> 3) & 1) << 1)) * 8);
    const int wm = wave >> 2, wn = wave & 3;
    const int a_base = lane_off + wm * 512;   // + mf*1024 per fragment
    const int b_base = lane_off + wn * 512;   // + nf*2048 per fragment

    #pragma unroll
    for (int t = 0; t < NT; ++t) {
        const u16* At = LdsA + (t & 3) * 8192;
        const u16* Bt = LdsB + (t & 3) * 8192;
        bf16x8 a[4], b[4], a2[4];

        // ---- phase 0: stage next A; read a,b; BAR; mf 0-3 x nf 0-3 ----
        if (t + 3 < NT) stage32(A + (t + 3) * BK, ld, LdsA + ((t + 3) & 3) * 8192, wave, lane);
        #pragma unroll
        for (int mf = 0; mf < 4; ++mf) a[mf] = *(const bf16x8*)(At + a_base + mf * 1024);
        #pragma unroll
        for (int nf = 0; nf < 4; ++nf) b[nf] = *(const bf16x8*)(Bt + b_base + nf * 2048);
        __builtin_amdgcn_sched_barrier(0);
        __builtin_amdgcn_s_barrier();
        __builtin_amdgcn_sched_barrier(0);
        __builtin_amdgcn_s_setprio(1);
        #pragma unroll
        for (int mf = 0; mf < 4; ++mf)
            #pragma unroll
            for (int nf = 0; nf < 4; ++nf)
                acc[mf][nf] = __builtin_amdgcn_mfma_f32_16x16x32_bf16(a[mf], b[nf], acc[mf][nf], 0, 0, 0);
        __builtin_amdgcn_s_setprio(0);
        __builtin_amdgcn_sched_barrier(0);
        __builtin_amdgcn_s_barrier();
        __builtin_amdgcn_sched_barrier(0);

        // ---- phase 1: stage next B; read a2; BAR; mf 4-7 x nf 0-3 (b reused) ----
        if (t + 3 < NT) stage32(B + (t + 3) * BK, ld, LdsB + ((t + 3) & 3) * 8192, wave, lane);
        #pragma unroll
        for (int mf = 0; mf < 4; ++mf) a2[mf] = *(const bf16x8*)(At + a_base + (mf + 4) * 1024);
        __builtin_amdgcn_sched_barrier(0);
        __builtin_amdgcn_s_barrier();
        __builtin_amdgcn_sched_barrier(0);
        __builtin_amdgcn_s_setprio(1);
        #pragma unroll
        for (int mf = 0; mf < 4; ++mf)
            #pragma unroll
            for (int nf = 0; nf < 4; ++nf)
                acc[mf + 4][nf] = __builtin_amdgcn_mfma_f32_16x16x32_bf16(a2[mf], b[nf], acc[mf + 4][nf], 0, 0, 0);
        __builtin_amdgcn_s_setprio(0);
        __builtin_amdgcn_sched_barrier(0);
        // paired counted waits (R12): only after odd t.
        if ((t & 1) == 1) {
            if (t < NT - 3)       vmwait<4>();
            else if (t == NT - 3) vmwait<0>();
        }
        __builtin_amdgcn_s_barrier();   // WAR guard for stage into slot (t+4)&3
        __builtin_amdgcn_sched_barrier(0);
    }
}

// out[m,d] = RoPE(x @ W^T + bias) as bf16; z selects projection.
// XCD-pinned A panels. Epilogue v2 (R9): RoPE in-register, bf16 dump to
// (dead) ring LDS with bank swizzle, coalesced dwordx4 stores (cacheable —
// logits re-reads this).
__global__ __launch_bounds__(512, 2) void proj_kernel(
    const u16* __restrict__ xbf,
    const u16* __restrict__ W0, const u16* __restrict__ W1,
    const u16* __restrict__ W2, const u16* __restrict__ W3,
    const float* __restrict__ b0, const float* __restrict__ b1,
    const float* __restrict__ b2, const float* __restrict__ b3,
    u16* __restrict__ o0, u16* __restrict__ o1, u16* __restrict__ o2, u16* __restrict__ o3,
    const uint32_t* __restrict__ cs_tab) {
    __shared__ __align__(16) u16 Lds[65536];   // 128 KiB: ring A | ring B, reused by epilogue
    u16* LdsA = Lds;
    u16* LdsB = Lds + 32768;
    const int tid = threadIdx.x, lane = tid & 63, wave = tid >> 6;
    const int bid = blockIdx.x;
    const int xcd = bid & 7, widx = bid >> 3;   // widx in [0,96)
    const int bx  = xcd * 8 + (widx & 7);       // xbf panel, pinned to this XCD
    const int t2  = widx >> 3;                  // 0..11 = z*3 + by
    const int z   = t2 / 3;
    const int by  = t2 - z * 3;
    const int m0 = bx * 256, n0 = by * 256;

    const u16*   W    = z == 0 ? W0 : z == 1 ? W1 : z == 2 ? W2 : W3;
    const float* bias = z == 0 ? b0 : z == 1 ? b1 : z == 2 ? b2 : b3;
    u16*         outp = z == 0 ? o0 : z == 1 ? o1 : z == 2 ? o2 : o3;

    f32x4 acc[8][4];
    #pragma unroll
    for (int x = 0; x < 8; ++x)
        #pragma unroll
        for (int y = 0; y < 4; ++y) acc[x][y] = f32x4{0.f, 0.f, 0.f, 0.f};

    gemm256_mainloop(xbf + (size_t)m0 * C_DIM, W + (size_t)n0 * C_DIM, C_DIM,
                     LdsA, LdsB, acc, wave, lane);

    // ---- epilogue v2 ----
    const int wm = wave >> 2, wn = wave & 3;
    const int g = lane >> 4, r = lane & 15;
    // (mainloop ends with drain + final barrier: all LDS traffic retired)
    #pragma unroll
    for (int nf = 0; nf < 4; ++nf) {
        const int colL = wn * 64 + nf * 16 + r;   // local col 0..255
        const int col  = n0 + colL;
        const float bv = bias[col];
        const float sgn = (col & 1) ? 1.0f : -1.0f;  // even d: -x_odd*sin ; odd d: +x_even*sin
        const uint32_t* csrow = cs_tab + (size_t)(col >> 1) * N_SEQ;
        #pragma unroll
        for (int mf = 0; mf < 8; ++mf) {
            const int rowb = m0 + mf * 32 + wm * 16 + g * 4;   // rows rowb..rowb+3
            const uint4 cs4 = *(const uint4*)(csrow + (rowb & (N_SEQ - 1)));
            #pragma unroll
            for (int i = 0; i < 4; ++i) {
                float v = acc[mf][nf][i] + bv;
                float p = __shfl_xor(v, 1);  // RoPE partner (col parity == lane parity)
                const uint32_t cs = ((const uint32_t*)&cs4)[i];
                const float c = __uint_as_float(cs << 16);
                const float s = __uint_as_float(cs & 0xFFFF0000u);
                const int rowL = mf * 32 + wm * 16 + g * 4 + i;
                const int ba = (rowL << 9) + colL * 2;          // [256][512B] tile
                *(u16*)((char*)Lds + (ba ^ (((rowL >> 2) & 3) << 5))) = f2bf(v * c + sgn * p * s);
            }
        }
    }
    __syncthreads();
    // readback (wave-uniform un-swizzle) + coalesced 16B stores: 1 KiB/wave-instr
    const size_t gbase = (size_t)m0 * C_DIM + n0;
    #pragma unroll
    for (int k = 0; k < 16; ++k) {
        const int f = (k * 512 + tid) * 16;
        const int row = f >> 9;
        const int cb  = f & 511;
        const uint4 vv = *(const uint4*)((const char*)Lds + (f ^ ((((unsigned)f >> 11) & 3) << 5)));
        *(uint4*)(outp + gbase + (size_t)row * C_DIM + (cb >> 1)) = vv;
    }
}

// out[z,n,m] = (Q[z,n,:].K[z,m,:])/sqrt(C) - (m<n)*1e10/sqrt(C);  z = h*8+b.
// Strictly-lower 256x256 blocks: reference fp32 computes (qk - 1e10) == -1e10
// exactly -> constant write, skip the GEMM (28/64 per z).
// R16: ALL output stores non-temporal (write-once stream, never re-read);
// nt-store uses clang-native f32x4 (HIP float4 is rejected by the builtin).
__global__ __launch_bounds__(512, 2) void logits_kernel(
    const u16* __restrict__ Q0, const u16* __restrict__ K0,
    const u16* __restrict__ Q1, const u16* __restrict__ K1,
    float* __restrict__ out) {
    __shared__ __align__(16) u16 LdsA[4 * 8192];
    __shared__ __align__(16) u16 LdsB[4 * 8192];
    const int tid = threadIdx.x, lane = tid & 63, wave = tid >> 6;
    const int bid = blockIdx.x;
    const int swz = (bid & 7) * 128 + (bid >> 3);
    const int z   = swz >> 6;          // 0..15 = h*8+b
    const int rem = swz & 63;
    const int by  = rem >> 3;          // row (Q) block
    const int bx  = rem & 7;           // col (K) block
    const int nrow0 = by * 256, mcol0 = bx * 256;

    const float RS = 0.036084391824351613f;  // 1/sqrt(768)
    const float MV = 1.0e10f * RS;
    float* outz = out + (size_t)z * N_SEQ * N_SEQ;

    if (bx < by) {  // fully-masked block: constant write, coalesced 1 KiB/wave nt stores
        const f32x4 cv = {-MV, -MV, -MV, -MV};
        #pragma unroll
        for (int i = 0; i < 32; ++i) {
            const int row = nrow0 + wave * 32 + i;
            __builtin_nontemporal_store(cv, (f32x4*)(outz + (size_t)row * N_SEQ + mcol0 + lane * 4));
        }
        return;
    }

    const int h = z >> 3, b = z & 7;
    const u16* Qb = (h ? Q1 : Q0) + (size_t)b * N_SEQ * C_DIM;
    const u16* Kb = (h ? K1 : K0) + (size_t)b * N_SEQ * C_DIM;

    f32x4 acc[8][4];
    #pragma unroll
    for (int x = 0; x < 8; ++x)
        #pragma unroll
        for (int y = 0; y < 4; ++y) acc[x][y] = f32x4{0.f, 0.f, 0.f, 0.f};

    gemm256_mainloop(Qb + (size_t)nrow0 * C_DIM, Kb + (size_t)mcol0 * C_DIM, C_DIM,
                     LdsA, LdsB, acc, wave, lane);

    const int wm = wave >> 2, wn = wave & 3;
    const int g = lane >> 4, r = lane & 15;
    #pragma unroll
    for (int mf = 0; mf < 8; ++mf) {
        #pragma unroll
        for (int i = 0; i < 4; ++i) {
            const int row = nrow0 + mf * 32 + wm * 16 + g * 4 + i;
            float* orow = outz + (size_t)row * N_SEQ;
            #pragma unroll
            for (int nf = 0; nf < 4; ++nf) {
                const int col = mcol0 + wn * 64 + nf * 16 + r;
                __builtin_nontemporal_store(acc[mf][nf][i] * RS - (col < row ? MV : 0.0f),
                                            orow + col);
            }
        }
    }
}

extern "C" void kernel_launch(void* const* d_in, const int* in_sizes, int n_in,
                              void* d_out, int out_size, void* d_ws, size_t ws_size,
                              hipStream_t stream) {
    (void)in_sizes; (void)n_in; (void)out_size; (void)ws_size;
    const float* feat = (const float*)d_in[0];
    const float* Wq   = (const float*)d_in[1];
    const float* bq   = (const float*)d_in[2];
    const float* Wk   = (const float*)d_in[3];
    const float* bk   = (const float*)d_in[4];
    const float* Wqc  = (const float*)d_in[5];
    const float* bqc  = (const float*)d_in[6];
    const float* Wkc  = (const float*)d_in[7];
    const float* bkc  = (const float*)d_in[8];
    float* out = (float*)d_out;

    // workspace layout (u16 elements): x_bf | W_bf[4] | Q0 K0 Q1 K1 | cs_tab (u32, [HALF_C][N_SEQ])
    u16* ws = (u16*)d_ws;
    const size_t XE = (size_t)M_TOT * C_DIM;   // 12,582,912
    const size_t WE = (size_t)C_DIM * C_DIM;   // 589,824
    u16* xbf = ws;
    u16* Wb0 = ws + XE;
    u16* Wb1 = Wb0 + WE;
    u16* Wb2 = Wb1 + WE;
    u16* Wb3 = Wb2 + WE;
    u16* qkbase = Wb3 + WE;
    u16* Qa = qkbase;            // proj0: Wq
    u16* Ka = qkbase + XE;       // proj1: Wk
    u16* Qc = qkbase + 2 * XE;   // proj2: Wq_cls
    u16* Kc = qkbase + 3 * XE;   // proj3: Wk_cls
    uint32_t* cs_tab = (uint32_t*)(qkbase + 4 * XE);

    prep_kernel<<<dim3(2048), dim3(256), 0, stream>>>(
        feat, Wq, Wk, Wqc, Wkc, xbf, Wb0, Wb1, Wb2, Wb3, cs_tab);

    proj_kernel<<<dim3(768), dim3(512), 0, stream>>>(
        xbf, Wb0, Wb1, Wb2, Wb3, bq, bk, bqc, bkc, Qa, Ka, Qc, Kc, cs_tab);

    logits_kernel<<<dim3(1024), dim3(512), 0, stream>>>(
        Qa, Ka, Qc, Kc, out);
}